// Round 1
// baseline (1133.967 us; speedup 1.0000x reference)
//
#include <hip/hip_runtime.h>
#include <cstdint>

#define N_FEATS_IN 256
#define HID 128
#define OUTF 64

// ---- CSR build ----------------------------------------------------------

__global__ __launch_bounds__(256) void count_deg_kernel(const int* __restrict__ ei, int E,
                                                        int* __restrict__ deg) {
  int e = blockIdx.x * 256 + threadIdx.x;
  if (e < E) atomicAdd(&deg[ei[E + e]], 1);  // col = target
}

__global__ __launch_bounds__(256) void dinv_kernel(const int* __restrict__ deg,
                                                   float* __restrict__ dinv, int n) {
  int i = blockIdx.x * 256 + threadIdx.x;
  if (i < n) dinv[i] = rsqrtf((float)(deg[i] + 1));  // +1 self-loop
}

// single-block two-phase exclusive scan: ptr[0..n], ptr[n] = total
__global__ __launch_bounds__(1024) void scan_kernel(const int* __restrict__ cnt,
                                                    int* __restrict__ ptr, int n) {
  __shared__ int tot[1024];
  int t = threadIdx.x;
  int per = (n + 1023) / 1024;
  int beg = t * per;
  int end = min(beg + per, n);
  int s = 0;
  for (int i = beg; i < end; ++i) s += cnt[i];
  tot[t] = s;
  __syncthreads();
  for (int off = 1; off < 1024; off <<= 1) {
    int v = (t >= off) ? tot[t - off] : 0;
    __syncthreads();
    tot[t] += v;
    __syncthreads();
  }
  int run = (t == 0) ? 0 : tot[t - 1];
  for (int i = beg; i < end; ++i) { ptr[i] = run; run += cnt[i]; }
  if (t == 1023) ptr[n] = run;
}

__global__ __launch_bounds__(256) void fill_kernel(const int* __restrict__ ei, int E,
    const int* __restrict__ ptr, int* __restrict__ cur, const float* __restrict__ dinv,
    int* __restrict__ csrc, float* __restrict__ cnrm) {
  int e = blockIdx.x * 256 + threadIdx.x;
  if (e < E) {
    int r = ei[e];       // source
    int c = ei[E + e];   // target
    int pos = ptr[c] + atomicAdd(&cur[c], 1);
    csrc[pos] = r;
    cnrm[pos] = dinv[r] * dinv[c];
  }
}

// ---- GEMM1: Y[N][128] = X[N][256] @ W1[256][128] ------------------------
// one thread per row, acc[128] in VGPRs, W via uniform (scalar) loads.

__global__ __launch_bounds__(64) void gemm1_kernel(const float* __restrict__ X,
    const float* __restrict__ W, float* __restrict__ Y, int nrows) {
  __shared__ float xs[32][65];  // transposed chunk xs[k][row], pad -> no bank conflicts
  const int tid = threadIdx.x;
  const int row0 = blockIdx.x * 64;
  const int row = row0 + tid;
  float acc[HID];
#pragma unroll
  for (int j = 0; j < HID; ++j) acc[j] = 0.f;

  for (int kb = 0; kb < N_FEATS_IN; kb += 32) {
    __syncthreads();
#pragma unroll
    for (int i = 0; i < 32; ++i) {
      int r = i * 2 + (tid >> 5);
      int k = tid & 31;
      int gr = row0 + r;
      xs[k][r] = (gr < nrows) ? X[(size_t)gr * N_FEATS_IN + kb + k] : 0.f;
    }
    __syncthreads();
#pragma unroll 1
    for (int kk = 0; kk < 32; ++kk) {
      float xv = xs[kk][tid];
      const float* __restrict__ wr = &W[(kb + kk) * HID];
#pragma unroll
      for (int j = 0; j < HID; ++j) acc[j] = fmaf(xv, wr[j], acc[j]);
    }
  }
  if (row < nrows) {
    float4* y4 = (float4*)&Y[(size_t)row * HID];
#pragma unroll
    for (int j = 0; j < HID / 4; ++j)
      y4[j] = make_float4(acc[4 * j], acc[4 * j + 1], acc[4 * j + 2], acc[4 * j + 3]);
  }
}

// ---- aggregation: Fout[c] = dinv[c]^2*Fin[c] + sum_e norm[e]*Fin[src[e]] -

__global__ __launch_bounds__(128) void agg_kernel(const float* __restrict__ Fin,
    const int* __restrict__ ptr, const int* __restrict__ csrc, const float* __restrict__ cnrm,
    const float* __restrict__ dinv, const float* __restrict__ bias,
    float* __restrict__ Fout, int do_relu) {
  const int c = blockIdx.x;
  const int f = threadIdx.x;
  const float d = dinv[c];
  float acc = d * d * Fin[(size_t)c * HID + f];
  const int beg = ptr[c], end = ptr[c + 1];
  int e = beg;
  for (; e + 4 <= end; e += 4) {
    int r0 = csrc[e], r1 = csrc[e + 1], r2 = csrc[e + 2], r3 = csrc[e + 3];
    float n0 = cnrm[e], n1 = cnrm[e + 1], n2 = cnrm[e + 2], n3 = cnrm[e + 3];
    float y0 = Fin[(size_t)r0 * HID + f];
    float y1 = Fin[(size_t)r1 * HID + f];
    float y2 = Fin[(size_t)r2 * HID + f];
    float y3 = Fin[(size_t)r3 * HID + f];
    acc = fmaf(n0, y0, acc);
    acc = fmaf(n1, y1, acc);
    acc = fmaf(n2, y2, acc);
    acc = fmaf(n3, y3, acc);
  }
  for (; e < end; ++e) acc = fmaf(cnrm[e], Fin[(size_t)csrc[e] * HID + f], acc);
  if (do_relu) acc = fmaxf(acc + bias[f], 0.f);
  Fout[(size_t)c * HID + f] = acc;
}

// ---- GEMM2: mu = G@Wmu + bmu ; lv = G@Wlv + blv -------------------------

__global__ __launch_bounds__(64) void gemm2_kernel(const float* __restrict__ G,
    const float* __restrict__ Wmu, const float* __restrict__ bmu,
    const float* __restrict__ Wlv, const float* __restrict__ blv,
    float* __restrict__ out, int nrows) {
  __shared__ float xs[32][65];
  const int tid = threadIdx.x;
  const int row0 = blockIdx.x * 64;
  const int row = row0 + tid;
  float amu[OUTF], alv[OUTF];
#pragma unroll
  for (int j = 0; j < OUTF; ++j) { amu[j] = bmu[j]; alv[j] = blv[j]; }

  for (int kb = 0; kb < HID; kb += 32) {
    __syncthreads();
#pragma unroll
    for (int i = 0; i < 32; ++i) {
      int r = i * 2 + (tid >> 5);
      int k = tid & 31;
      int gr = row0 + r;
      xs[k][r] = (gr < nrows) ? G[(size_t)gr * HID + kb + k] : 0.f;
    }
    __syncthreads();
#pragma unroll 1
    for (int kk = 0; kk < 32; ++kk) {
      float xv = xs[kk][tid];
      const float* __restrict__ wm = &Wmu[(kb + kk) * OUTF];
      const float* __restrict__ wl = &Wlv[(kb + kk) * OUTF];
#pragma unroll
      for (int j = 0; j < OUTF; ++j) {
        amu[j] = fmaf(xv, wm[j], amu[j]);
        alv[j] = fmaf(xv, wl[j], alv[j]);
      }
    }
  }
  if (row < nrows) {
    float4* m4 = (float4*)&out[(size_t)row * OUTF];
    float4* l4 = (float4*)&out[(size_t)nrows * OUTF + (size_t)row * OUTF];
#pragma unroll
    for (int j = 0; j < OUTF / 4; ++j) {
      m4[j] = make_float4(amu[4 * j], amu[4 * j + 1], amu[4 * j + 2], amu[4 * j + 3]);
      l4[j] = make_float4(alv[4 * j], alv[4 * j + 1], alv[4 * j + 2], alv[4 * j + 3]);
    }
  }
}

// ---- launch -------------------------------------------------------------

extern "C" void kernel_launch(void* const* d_in, const int* in_sizes, int n_in,
                              void* d_out, int out_size, void* d_ws, size_t ws_size,
                              hipStream_t stream) {
  const float* X   = (const float*)d_in[0];
  const int*   ei  = (const int*)d_in[1];   // int32 (JAX x64 disabled)
  const float* W1  = (const float*)d_in[2];
  const float* b1  = (const float*)d_in[3];
  const float* Wmu = (const float*)d_in[4];
  const float* bmu = (const float*)d_in[5];
  const float* Wlv = (const float*)d_in[6];
  const float* blv = (const float*)d_in[7];
  float* out = (float*)d_out;

  const int N = in_sizes[0] / N_FEATS_IN;   // 100000
  const int E = in_sizes[1] / 2;            // 1600000

  char* ws = (char*)d_ws;
  size_t off = 0;
  auto alloc = [&](size_t bytes) -> void* {
    void* p = ws + off;
    off += (bytes + 255) & ~(size_t)255;
    return p;
  };
  float* Y    = (float*)alloc((size_t)N * HID * 4);  // layer-1 transform; reused as G
  float* H    = (float*)alloc((size_t)N * HID * 4);  // relu(Â Y + b1)
  float* dinv = (float*)alloc((size_t)N * 4);
  int*   deg  = (int*)alloc((size_t)N * 4);
  int*   ptr  = (int*)alloc((size_t)(N + 1) * 4);
  int*   cur  = (int*)alloc((size_t)N * 4);
  int*   csrc = (int*)alloc((size_t)E * 4);
  float* cnrm = (float*)alloc((size_t)E * 4);
  (void)ws_size; (void)n_in; (void)out_size;

  hipMemsetAsync(deg, 0, (size_t)N * 4, stream);
  hipMemsetAsync(cur, 0, (size_t)N * 4, stream);

  int ge = (E + 255) / 256;
  int gn = (N + 255) / 256;
  count_deg_kernel<<<ge, 256, 0, stream>>>(ei, E, deg);
  dinv_kernel<<<gn, 256, 0, stream>>>(deg, dinv, N);
  scan_kernel<<<1, 1024, 0, stream>>>(deg, ptr, N);
  fill_kernel<<<ge, 256, 0, stream>>>(ei, E, ptr, cur, dinv, csrc, cnrm);

  int grows = (N + 63) / 64;
  gemm1_kernel<<<grows, 64, 0, stream>>>(X, W1, Y, N);
  agg_kernel<<<N, HID, 0, stream>>>(Y, ptr, csrc, cnrm, dinv, b1, H, 1);   // H = relu(ÂY + b1)
  agg_kernel<<<N, HID, 0, stream>>>(H, ptr, csrc, cnrm, dinv, b1, Y, 0);   // G = ÂH (one pass for mu+lv)
  gemm2_kernel<<<grows, 64, 0, stream>>>(Y, Wmu, bmu, Wlv, blv, out, N);
}

// Round 2
// 696.291 us; speedup vs baseline: 1.6286x; 1.6286x over previous
//
#include <hip/hip_runtime.h>
#include <hip/hip_bf16.h>
#include <cstdint>

#define N_FEATS_IN 256
#define HID 128
#define OUTF 64

typedef __bf16 bf16x8 __attribute__((ext_vector_type(8)));
typedef __bf16 bf16x2 __attribute__((ext_vector_type(2)));
typedef float f32x4 __attribute__((ext_vector_type(4)));

// ---- CSR build ----------------------------------------------------------

__global__ __launch_bounds__(256) void count_deg_kernel(const int* __restrict__ ei, int E,
                                                        int* __restrict__ deg) {
  int e = blockIdx.x * 256 + threadIdx.x;
  if (e < E) atomicAdd(&deg[ei[E + e]], 1);  // col = target
}

__global__ __launch_bounds__(256) void dinv_kernel(const int* __restrict__ deg,
                                                   float* __restrict__ dinv, int n) {
  int i = blockIdx.x * 256 + threadIdx.x;
  if (i < n) dinv[i] = rsqrtf((float)(deg[i] + 1));  // +1 self-loop
}

// single-block two-phase exclusive scan: ptr[0..n], ptr[n] = total
__global__ __launch_bounds__(1024) void scan_kernel(const int* __restrict__ cnt,
                                                    int* __restrict__ ptr, int n) {
  __shared__ int tot[1024];
  int t = threadIdx.x;
  int per = (n + 1023) / 1024;
  int beg = t * per;
  int end = min(beg + per, n);
  int s = 0;
  for (int i = beg; i < end; ++i) s += cnt[i];
  tot[t] = s;
  __syncthreads();
  for (int off = 1; off < 1024; off <<= 1) {
    int v = (t >= off) ? tot[t - off] : 0;
    __syncthreads();
    tot[t] += v;
    __syncthreads();
  }
  int run = (t == 0) ? 0 : tot[t - 1];
  for (int i = beg; i < end; ++i) { ptr[i] = run; run += cnt[i]; }
  if (t == 1023) ptr[n] = run;
}

__global__ __launch_bounds__(256) void fill_kernel(const int* __restrict__ ei, int E,
    const int* __restrict__ ptr, int* __restrict__ cur, const float* __restrict__ dinv,
    int* __restrict__ csrc, float* __restrict__ cnrm) {
  int e = blockIdx.x * 256 + threadIdx.x;
  if (e < E) {
    int r = ei[e];       // source
    int c = ei[E + e];   // target
    int pos = ptr[c] + atomicAdd(&cur[c], 1);
    csrc[pos] = r;
    cnrm[pos] = dinv[r] * dinv[c];
  }
}

// ---- weight repack into MFMA B-fragment order ---------------------------
// B-frag for mfma_f32_16x16x32_bf16: lane l holds B[k = (l>>4)*8 + j][n = l&15]
// packed[( (s*8 + t)*64 + l )*8 + j] = W[(s*32 + (l>>4)*8 + j)*NCOL + t*16 + (l&15)]

__global__ __launch_bounds__(256) void pack_w1_kernel(const float* __restrict__ W,
                                                      __bf16* __restrict__ Wp) {
  int idx = blockIdx.x * 256 + threadIdx.x;  // 8s * 8t * 64l * 8j = 32768
  if (idx >= 32768) return;
  int j = idx & 7, l = (idx >> 3) & 63, t = (idx >> 9) & 7, s = idx >> 12;
  int k = s * 32 + (l >> 4) * 8 + j;
  int n = t * 16 + (l & 15);
  Wp[idx] = (__bf16)W[k * HID + n];
}

__global__ __launch_bounds__(256) void pack_wc_kernel(const float* __restrict__ Wmu,
    const float* __restrict__ Wlv, __bf16* __restrict__ Wp) {
  int idx = blockIdx.x * 256 + threadIdx.x;  // 4s * 8t * 64l * 8j = 16384
  if (idx >= 16384) return;
  int j = idx & 7, l = (idx >> 3) & 63, t = (idx >> 9) & 7, s = idx >> 12;
  int k = s * 32 + (l >> 4) * 8 + j;
  int g = t * 16 + (l & 15);
  float v = (g < OUTF) ? Wmu[k * OUTF + g] : Wlv[k * OUTF + (g - OUTF)];
  Wp[idx] = (__bf16)v;
}

// ---- GEMM1 (MFMA): Yb[N][128] = bf16( X[N][256] @ W1 ) ------------------
// block = 256 thr = 4 waves; wave = 32 rows x 128 cols; A from global f32
// (converted in-register), B from packed frags, no LDS, no barriers.

__global__ __launch_bounds__(256) void gemm1_mfma(const float* __restrict__ X,
    const __bf16* __restrict__ Wp, __bf16* __restrict__ Yb, int nrows) {
  const int lane = threadIdx.x & 63;
  const int wave = threadIdx.x >> 6;
  const int rb = blockIdx.x * 128 + wave * 32;
  const int lm = lane & 15;
  const int q = lane >> 4;

  f32x4 acc[2][8];
#pragma unroll
  for (int m = 0; m < 2; ++m)
#pragma unroll
    for (int t = 0; t < 8; ++t) acc[m][t] = (f32x4)0.f;

  int r0 = min(rb + lm, nrows - 1);
  int r1 = min(rb + 16 + lm, nrows - 1);
  const float* x0 = X + (size_t)r0 * N_FEATS_IN + q * 8;
  const float* x1 = X + (size_t)r1 * N_FEATS_IN + q * 8;
  const bf16x8* wp = (const bf16x8*)Wp;

#pragma unroll
  for (int s = 0; s < 8; ++s) {
    float4 u0 = ((const float4*)(x0 + s * 32))[0];
    float4 v0 = ((const float4*)(x0 + s * 32))[1];
    float4 u1 = ((const float4*)(x1 + s * 32))[0];
    float4 v1 = ((const float4*)(x1 + s * 32))[1];
    bf16x8 a0, a1;
    a0[0] = (__bf16)u0.x; a0[1] = (__bf16)u0.y; a0[2] = (__bf16)u0.z; a0[3] = (__bf16)u0.w;
    a0[4] = (__bf16)v0.x; a0[5] = (__bf16)v0.y; a0[6] = (__bf16)v0.z; a0[7] = (__bf16)v0.w;
    a1[0] = (__bf16)u1.x; a1[1] = (__bf16)u1.y; a1[2] = (__bf16)u1.z; a1[3] = (__bf16)u1.w;
    a1[4] = (__bf16)v1.x; a1[5] = (__bf16)v1.y; a1[6] = (__bf16)v1.z; a1[7] = (__bf16)v1.w;
#pragma unroll
    for (int t = 0; t < 8; ++t) {
      bf16x8 b = wp[(s * 8 + t) * 64 + lane];
      acc[0][t] = __builtin_amdgcn_mfma_f32_16x16x32_bf16(a0, b, acc[0][t], 0, 0, 0);
      acc[1][t] = __builtin_amdgcn_mfma_f32_16x16x32_bf16(a1, b, acc[1][t], 0, 0, 0);
    }
  }
  // D: col = lane&15, row = q*4 + reg
#pragma unroll
  for (int m = 0; m < 2; ++m) {
    int rowbase = rb + m * 16 + q * 4;
#pragma unroll
    for (int t = 0; t < 8; ++t) {
#pragma unroll
      for (int r = 0; r < 4; ++r) {
        int row = rowbase + r;
        if (row < nrows) Yb[(size_t)row * HID + t * 16 + lm] = (__bf16)acc[m][t][r];
      }
    }
  }
}

// ---- aggregation (bf16 in/out, f32 accumulate) --------------------------
// Fout[c] = dinv[c]^2*Fin[c] + sum_e cnrm[e]*Fin[csrc[e]]; 1 wave/node, 2 feats/lane

__global__ __launch_bounds__(64) void agg_kernel(const __bf16* __restrict__ Fin,
    const int* __restrict__ ptr, const int* __restrict__ csrc, const float* __restrict__ cnrm,
    const float* __restrict__ dinv, const float* __restrict__ bias,
    __bf16* __restrict__ Fout, int do_relu) {
  const int c = blockIdx.x;
  const int t = threadIdx.x;
  const float d = dinv[c];
  bf16x2 sv = ((const bf16x2*)(Fin + (size_t)c * HID))[t];
  float ax = d * d * (float)sv[0];
  float ay = d * d * (float)sv[1];
  const int beg = ptr[c], end = ptr[c + 1];
  int e = beg;
  for (; e + 4 <= end; e += 4) {
    int r0 = csrc[e], r1 = csrc[e + 1], r2 = csrc[e + 2], r3 = csrc[e + 3];
    float n0 = cnrm[e], n1 = cnrm[e + 1], n2 = cnrm[e + 2], n3 = cnrm[e + 3];
    bf16x2 v0 = ((const bf16x2*)(Fin + (size_t)r0 * HID))[t];
    bf16x2 v1 = ((const bf16x2*)(Fin + (size_t)r1 * HID))[t];
    bf16x2 v2 = ((const bf16x2*)(Fin + (size_t)r2 * HID))[t];
    bf16x2 v3 = ((const bf16x2*)(Fin + (size_t)r3 * HID))[t];
    ax = fmaf(n0, (float)v0[0], ax); ay = fmaf(n0, (float)v0[1], ay);
    ax = fmaf(n1, (float)v1[0], ax); ay = fmaf(n1, (float)v1[1], ay);
    ax = fmaf(n2, (float)v2[0], ax); ay = fmaf(n2, (float)v2[1], ay);
    ax = fmaf(n3, (float)v3[0], ax); ay = fmaf(n3, (float)v3[1], ay);
  }
  for (; e < end; ++e) {
    bf16x2 v = ((const bf16x2*)(Fin + (size_t)csrc[e] * HID))[t];
    float nn = cnrm[e];
    ax = fmaf(nn, (float)v[0], ax);
    ay = fmaf(nn, (float)v[1], ay);
  }
  if (do_relu) {
    ax = fmaxf(ax + bias[2 * t], 0.f);
    ay = fmaxf(ay + bias[2 * t + 1], 0.f);
  }
  bf16x2 o;
  o[0] = (__bf16)ax;
  o[1] = (__bf16)ay;
  ((bf16x2*)(Fout + (size_t)c * HID))[t] = o;
}

// ---- GEMM2 (MFMA): [mu|lv] = Gb[N][128] @ Wc[128][128] + bias -----------

__global__ __launch_bounds__(256) void gemm2_mfma(const __bf16* __restrict__ Gb,
    const __bf16* __restrict__ Wp, const float* __restrict__ bmu,
    const float* __restrict__ blv, float* __restrict__ out, int nrows) {
  const int lane = threadIdx.x & 63;
  const int wave = threadIdx.x >> 6;
  const int rb = blockIdx.x * 128 + wave * 32;
  const int lm = lane & 15;
  const int q = lane >> 4;

  f32x4 acc[2][8];
#pragma unroll
  for (int m = 0; m < 2; ++m)
#pragma unroll
    for (int t = 0; t < 8; ++t) acc[m][t] = (f32x4)0.f;

  int r0 = min(rb + lm, nrows - 1);
  int r1 = min(rb + 16 + lm, nrows - 1);
  const __bf16* g0 = Gb + (size_t)r0 * HID + q * 8;
  const __bf16* g1 = Gb + (size_t)r1 * HID + q * 8;
  const bf16x8* wp = (const bf16x8*)Wp;

#pragma unroll
  for (int s = 0; s < 4; ++s) {
    bf16x8 a0 = *(const bf16x8*)(g0 + s * 32);
    bf16x8 a1 = *(const bf16x8*)(g1 + s * 32);
#pragma unroll
    for (int t = 0; t < 8; ++t) {
      bf16x8 b = wp[(s * 8 + t) * 64 + lane];
      acc[0][t] = __builtin_amdgcn_mfma_f32_16x16x32_bf16(a0, b, acc[0][t], 0, 0, 0);
      acc[1][t] = __builtin_amdgcn_mfma_f32_16x16x32_bf16(a1, b, acc[1][t], 0, 0, 0);
    }
  }
#pragma unroll
  for (int m = 0; m < 2; ++m) {
    int rowbase = rb + m * 16 + q * 4;
#pragma unroll
    for (int t = 0; t < 8; ++t) {
      int g = t * 16 + lm;
      float bv = (g < OUTF) ? bmu[g] : blv[g - OUTF];
      float* ob = (g < OUTF) ? (out + g) : (out + (size_t)nrows * OUTF + (g - OUTF));
#pragma unroll
      for (int r = 0; r < 4; ++r) {
        int row = rowbase + r;
        if (row < nrows) ob[(size_t)row * OUTF] = acc[m][t][r] + bv;
      }
    }
  }
}

// ---- launch -------------------------------------------------------------

extern "C" void kernel_launch(void* const* d_in, const int* in_sizes, int n_in,
                              void* d_out, int out_size, void* d_ws, size_t ws_size,
                              hipStream_t stream) {
  const float* X   = (const float*)d_in[0];
  const int*   ei  = (const int*)d_in[1];
  const float* W1  = (const float*)d_in[2];
  const float* b1  = (const float*)d_in[3];
  const float* Wmu = (const float*)d_in[4];
  const float* bmu = (const float*)d_in[5];
  const float* Wlv = (const float*)d_in[6];
  const float* blv = (const float*)d_in[7];
  float* out = (float*)d_out;

  const int N = in_sizes[0] / N_FEATS_IN;   // 100000
  const int E = in_sizes[1] / 2;            // 1600000

  char* ws = (char*)d_ws;
  size_t off = 0;
  auto alloc = [&](size_t bytes) -> void* {
    void* p = ws + off;
    off += (bytes + 255) & ~(size_t)255;
    return p;
  };
  __bf16* Yb  = (__bf16*)alloc((size_t)N * HID * 2);  // gemm1 out; reused as G
  __bf16* Hb  = (__bf16*)alloc((size_t)N * HID * 2);  // relu(Â Y + b1)
  float* dinv = (float*)alloc((size_t)N * 4);
  int*   deg  = (int*)alloc((size_t)N * 4);
  int*   ptr  = (int*)alloc((size_t)(N + 1) * 4);
  int*   cur  = (int*)alloc((size_t)N * 4);
  int*   csrc = (int*)alloc((size_t)E * 4);
  float* cnrm = (float*)alloc((size_t)E * 4);
  __bf16* W1p = (__bf16*)alloc(32768 * 2);
  __bf16* Wcp = (__bf16*)alloc(16384 * 2);
  (void)ws_size; (void)n_in; (void)out_size;

  hipMemsetAsync(deg, 0, (size_t)N * 4, stream);
  hipMemsetAsync(cur, 0, (size_t)N * 4, stream);

  int ge = (E + 255) / 256;
  int gn = (N + 255) / 256;
  count_deg_kernel<<<ge, 256, 0, stream>>>(ei, E, deg);
  dinv_kernel<<<gn, 256, 0, stream>>>(deg, dinv, N);
  scan_kernel<<<1, 1024, 0, stream>>>(deg, ptr, N);
  fill_kernel<<<ge, 256, 0, stream>>>(ei, E, ptr, cur, dinv, csrc, cnrm);
  pack_w1_kernel<<<128, 256, 0, stream>>>(W1, W1p);
  pack_wc_kernel<<<64, 256, 0, stream>>>(Wmu, Wlv, Wcp);

  int gblk = (N + 127) / 128;
  gemm1_mfma<<<gblk, 256, 0, stream>>>(X, W1p, Yb, N);
  agg_kernel<<<N, 64, 0, stream>>>(Yb, ptr, csrc, cnrm, dinv, b1, Hb, 1);  // H = relu(ÂY+b1)
  agg_kernel<<<N, 64, 0, stream>>>(Hb, ptr, csrc, cnrm, dinv, b1, Yb, 0);  // G = ÂH
  gemm2_mfma<<<gblk, 256, 0, stream>>>(Yb, Wcp, bmu, blv, out, N);
}

// Round 3
// 547.358 us; speedup vs baseline: 2.0717x; 1.2721x over previous
//
#include <hip/hip_runtime.h>
#include <hip/hip_bf16.h>
#include <cstdint>

#define N_FEATS_IN 256
#define HID 128
#define OUTF 64
#define SITEMS 8  // elements per thread in hierarchical scan; 256*8=2048/block

typedef __bf16 bf16x8 __attribute__((ext_vector_type(8)));
typedef __bf16 bf16x2 __attribute__((ext_vector_type(2)));
typedef float f32x4 __attribute__((ext_vector_type(4)));

// ---- CSR build ----------------------------------------------------------

__global__ __launch_bounds__(256) void count_deg_kernel(const int* __restrict__ ei, int E,
                                                        int* __restrict__ deg) {
  int e = blockIdx.x * 256 + threadIdx.x;
  if (e < E) atomicAdd(&deg[ei[E + e]], 1);  // col = target
}

__global__ __launch_bounds__(256) void dinv_kernel(const int* __restrict__ deg,
                                                   float* __restrict__ dinv, int n) {
  int i = blockIdx.x * 256 + threadIdx.x;
  if (i < n) dinv[i] = rsqrtf((float)(deg[i] + 1));  // +1 self-loop
}

// ---- hierarchical exclusive scan: ptr[0..n], ptr[n] = total -------------

__global__ __launch_bounds__(256) void scan_part_kernel(const int* __restrict__ cnt, int n,
                                                        int* __restrict__ bsum) {
  __shared__ int ts[256];
  const int t = threadIdx.x;
  int base = (blockIdx.x * 256 + t) * SITEMS;
  int s = 0;
#pragma unroll
  for (int i = 0; i < SITEMS; ++i) {
    int idx = base + i;
    if (idx < n) s += cnt[idx];
  }
  ts[t] = s;
  __syncthreads();
  for (int off = 128; off > 0; off >>= 1) {
    if (t < off) ts[t] += ts[t + off];
    __syncthreads();
  }
  if (t == 0) bsum[blockIdx.x] = ts[0];
}

__global__ __launch_bounds__(256) void scan_bsum_kernel(int* __restrict__ bsum, int nb) {
  __shared__ int ts[256];
  const int t = threadIdx.x;
  int v = (t < nb) ? bsum[t] : 0;
  ts[t] = v;
  __syncthreads();
  for (int off = 1; off < 256; off <<= 1) {
    int u = (t >= off) ? ts[t - off] : 0;
    __syncthreads();
    ts[t] += u;
    __syncthreads();
  }
  if (t < nb) bsum[t] = ts[t] - v;  // exclusive
}

__global__ __launch_bounds__(256) void scan_final_kernel(const int* __restrict__ cnt, int n,
    const int* __restrict__ bsum, int* __restrict__ ptr) {
  __shared__ int ts[256];
  const int t = threadIdx.x;
  int base = (blockIdx.x * 256 + t) * SITEMS;
  int loc[SITEMS];
  int s = 0;
#pragma unroll
  for (int i = 0; i < SITEMS; ++i) {
    int idx = base + i;
    loc[i] = (idx < n) ? cnt[idx] : 0;
    s += loc[i];
  }
  ts[t] = s;
  __syncthreads();
  for (int off = 1; off < 256; off <<= 1) {
    int u = (t >= off) ? ts[t - off] : 0;
    __syncthreads();
    ts[t] += u;
    __syncthreads();
  }
  int run = bsum[blockIdx.x] + ts[t] - s;  // exclusive prefix for this thread
#pragma unroll
  for (int i = 0; i < SITEMS; ++i) {
    int idx = base + i;
    if (idx < n) ptr[idx] = run;
    run += loc[i];
  }
  if (base < n && base + SITEMS >= n) ptr[n] = run;  // thread covering n-1
}

__global__ __launch_bounds__(256) void fill_kernel(const int* __restrict__ ei, int E,
    const int* __restrict__ ptr, int* __restrict__ cur, const float* __restrict__ dinv,
    int* __restrict__ csrc, float* __restrict__ cnrm) {
  int e = blockIdx.x * 256 + threadIdx.x;
  if (e < E) {
    int r = ei[e];       // source
    int c = ei[E + e];   // target
    int pos = ptr[c] + atomicAdd(&cur[c], 1);
    csrc[pos] = r;
    cnrm[pos] = dinv[r] * dinv[c];
  }
}

// ---- weight repack into MFMA B-fragment order ---------------------------
// B-frag for mfma_f32_16x16x32_bf16: lane l holds B[k = (l>>4)*8 + j][n = l&15]

__global__ __launch_bounds__(256) void pack_w1_kernel(const float* __restrict__ W,
                                                      __bf16* __restrict__ Wp) {
  int idx = blockIdx.x * 256 + threadIdx.x;  // 8s * 8t * 64l * 8j = 32768
  if (idx >= 32768) return;
  int j = idx & 7, l = (idx >> 3) & 63, t = (idx >> 9) & 7, s = idx >> 12;
  int k = s * 32 + (l >> 4) * 8 + j;
  int n = t * 16 + (l & 15);
  Wp[idx] = (__bf16)W[k * HID + n];
}

__global__ __launch_bounds__(256) void pack_wc_kernel(const float* __restrict__ Wmu,
    const float* __restrict__ Wlv, __bf16* __restrict__ Wp) {
  int idx = blockIdx.x * 256 + threadIdx.x;  // 4s * 8t * 64l * 8j = 16384
  if (idx >= 16384) return;
  int j = idx & 7, l = (idx >> 3) & 63, t = (idx >> 9) & 7, s = idx >> 12;
  int k = s * 32 + (l >> 4) * 8 + j;
  int g = t * 16 + (l & 15);
  float v = (g < OUTF) ? Wmu[k * OUTF + g] : Wlv[k * OUTF + (g - OUTF)];
  Wp[idx] = (__bf16)v;
}

// ---- GEMM1 (MFMA): Yb[N][128] = bf16( X[N][256] @ W1 ) ------------------

__global__ __launch_bounds__(256) void gemm1_mfma(const float* __restrict__ X,
    const __bf16* __restrict__ Wp, __bf16* __restrict__ Yb, int nrows) {
  const int lane = threadIdx.x & 63;
  const int wave = threadIdx.x >> 6;
  const int rb = blockIdx.x * 128 + wave * 32;
  const int lm = lane & 15;
  const int q = lane >> 4;

  f32x4 acc[2][8];
#pragma unroll
  for (int m = 0; m < 2; ++m)
#pragma unroll
    for (int t = 0; t < 8; ++t) acc[m][t] = (f32x4)0.f;

  int r0 = min(rb + lm, nrows - 1);
  int r1 = min(rb + 16 + lm, nrows - 1);
  const float* x0 = X + (size_t)r0 * N_FEATS_IN + q * 8;
  const float* x1 = X + (size_t)r1 * N_FEATS_IN + q * 8;
  const bf16x8* wp = (const bf16x8*)Wp;

#pragma unroll
  for (int s = 0; s < 8; ++s) {
    float4 u0 = ((const float4*)(x0 + s * 32))[0];
    float4 v0 = ((const float4*)(x0 + s * 32))[1];
    float4 u1 = ((const float4*)(x1 + s * 32))[0];
    float4 v1 = ((const float4*)(x1 + s * 32))[1];
    bf16x8 a0, a1;
    a0[0] = (__bf16)u0.x; a0[1] = (__bf16)u0.y; a0[2] = (__bf16)u0.z; a0[3] = (__bf16)u0.w;
    a0[4] = (__bf16)v0.x; a0[5] = (__bf16)v0.y; a0[6] = (__bf16)v0.z; a0[7] = (__bf16)v0.w;
    a1[0] = (__bf16)u1.x; a1[1] = (__bf16)u1.y; a1[2] = (__bf16)u1.z; a1[3] = (__bf16)u1.w;
    a1[4] = (__bf16)v1.x; a1[5] = (__bf16)v1.y; a1[6] = (__bf16)v1.z; a1[7] = (__bf16)v1.w;
#pragma unroll
    for (int t = 0; t < 8; ++t) {
      bf16x8 b = wp[(s * 8 + t) * 64 + lane];
      acc[0][t] = __builtin_amdgcn_mfma_f32_16x16x32_bf16(a0, b, acc[0][t], 0, 0, 0);
      acc[1][t] = __builtin_amdgcn_mfma_f32_16x16x32_bf16(a1, b, acc[1][t], 0, 0, 0);
    }
  }
  // D: col = lane&15, row = q*4 + reg
#pragma unroll
  for (int m = 0; m < 2; ++m) {
    int rowbase = rb + m * 16 + q * 4;
#pragma unroll
    for (int t = 0; t < 8; ++t) {
#pragma unroll
      for (int r = 0; r < 4; ++r) {
        int row = rowbase + r;
        if (row < nrows) Yb[(size_t)row * HID + t * 16 + lm] = (__bf16)acc[m][t][r];
      }
    }
  }
}

// ---- aggregation (bf16 in/out, f32 accumulate) --------------------------

__global__ __launch_bounds__(64) void agg_kernel(const __bf16* __restrict__ Fin,
    const int* __restrict__ ptr, const int* __restrict__ csrc, const float* __restrict__ cnrm,
    const float* __restrict__ dinv, const float* __restrict__ bias,
    __bf16* __restrict__ Fout, int do_relu) {
  const int c = blockIdx.x;
  const int t = threadIdx.x;
  const float d = dinv[c];
  bf16x2 sv = ((const bf16x2*)(Fin + (size_t)c * HID))[t];
  float ax = d * d * (float)sv[0];
  float ay = d * d * (float)sv[1];
  const int beg = ptr[c], end = ptr[c + 1];
  int e = beg;
  for (; e + 4 <= end; e += 4) {
    int r0 = csrc[e], r1 = csrc[e + 1], r2 = csrc[e + 2], r3 = csrc[e + 3];
    float n0 = cnrm[e], n1 = cnrm[e + 1], n2 = cnrm[e + 2], n3 = cnrm[e + 3];
    bf16x2 v0 = ((const bf16x2*)(Fin + (size_t)r0 * HID))[t];
    bf16x2 v1 = ((const bf16x2*)(Fin + (size_t)r1 * HID))[t];
    bf16x2 v2 = ((const bf16x2*)(Fin + (size_t)r2 * HID))[t];
    bf16x2 v3 = ((const bf16x2*)(Fin + (size_t)r3 * HID))[t];
    ax = fmaf(n0, (float)v0[0], ax); ay = fmaf(n0, (float)v0[1], ay);
    ax = fmaf(n1, (float)v1[0], ax); ay = fmaf(n1, (float)v1[1], ay);
    ax = fmaf(n2, (float)v2[0], ax); ay = fmaf(n2, (float)v2[1], ay);
    ax = fmaf(n3, (float)v3[0], ax); ay = fmaf(n3, (float)v3[1], ay);
  }
  for (; e < end; ++e) {
    bf16x2 v = ((const bf16x2*)(Fin + (size_t)csrc[e] * HID))[t];
    float nn = cnrm[e];
    ax = fmaf(nn, (float)v[0], ax);
    ay = fmaf(nn, (float)v[1], ay);
  }
  if (do_relu) {
    ax = fmaxf(ax + bias[2 * t], 0.f);
    ay = fmaxf(ay + bias[2 * t + 1], 0.f);
  }
  bf16x2 o;
  o[0] = (__bf16)ax;
  o[1] = (__bf16)ay;
  ((bf16x2*)(Fout + (size_t)c * HID))[t] = o;
}

// ---- GEMM2 (MFMA): [mu|lv] = Gb[N][128] @ Wc[128][128] + bias -----------

__global__ __launch_bounds__(256) void gemm2_mfma(const __bf16* __restrict__ Gb,
    const __bf16* __restrict__ Wp, const float* __restrict__ bmu,
    const float* __restrict__ blv, float* __restrict__ out, int nrows) {
  const int lane = threadIdx.x & 63;
  const int wave = threadIdx.x >> 6;
  const int rb = blockIdx.x * 128 + wave * 32;
  const int lm = lane & 15;
  const int q = lane >> 4;

  f32x4 acc[2][8];
#pragma unroll
  for (int m = 0; m < 2; ++m)
#pragma unroll
    for (int t = 0; t < 8; ++t) acc[m][t] = (f32x4)0.f;

  int r0 = min(rb + lm, nrows - 1);
  int r1 = min(rb + 16 + lm, nrows - 1);
  const __bf16* g0 = Gb + (size_t)r0 * HID + q * 8;
  const __bf16* g1 = Gb + (size_t)r1 * HID + q * 8;
  const bf16x8* wp = (const bf16x8*)Wp;

#pragma unroll
  for (int s = 0; s < 4; ++s) {
    bf16x8 a0 = *(const bf16x8*)(g0 + s * 32);
    bf16x8 a1 = *(const bf16x8*)(g1 + s * 32);
#pragma unroll
    for (int t = 0; t < 8; ++t) {
      bf16x8 b = wp[(s * 8 + t) * 64 + lane];
      acc[0][t] = __builtin_amdgcn_mfma_f32_16x16x32_bf16(a0, b, acc[0][t], 0, 0, 0);
      acc[1][t] = __builtin_amdgcn_mfma_f32_16x16x32_bf16(a1, b, acc[1][t], 0, 0, 0);
    }
  }
#pragma unroll
  for (int m = 0; m < 2; ++m) {
    int rowbase = rb + m * 16 + q * 4;
#pragma unroll
    for (int t = 0; t < 8; ++t) {
      int g = t * 16 + lm;
      float bv = (g < OUTF) ? bmu[g] : blv[g - OUTF];
      float* ob = (g < OUTF) ? (out + g) : (out + (size_t)nrows * OUTF + (g - OUTF));
#pragma unroll
      for (int r = 0; r < 4; ++r) {
        int row = rowbase + r;
        if (row < nrows) ob[(size_t)row * OUTF] = acc[m][t][r] + bv;
      }
    }
  }
}

// ---- launch -------------------------------------------------------------

extern "C" void kernel_launch(void* const* d_in, const int* in_sizes, int n_in,
                              void* d_out, int out_size, void* d_ws, size_t ws_size,
                              hipStream_t stream) {
  const float* X   = (const float*)d_in[0];
  const int*   ei  = (const int*)d_in[1];
  const float* W1  = (const float*)d_in[2];
  const float* b1  = (const float*)d_in[3];
  const float* Wmu = (const float*)d_in[4];
  const float* bmu = (const float*)d_in[5];
  const float* Wlv = (const float*)d_in[6];
  const float* blv = (const float*)d_in[7];
  float* out = (float*)d_out;

  const int N = in_sizes[0] / N_FEATS_IN;   // 100000
  const int E = in_sizes[1] / 2;            // 1600000

  char* ws = (char*)d_ws;
  size_t off = 0;
  auto alloc = [&](size_t bytes) -> void* {
    void* p = ws + off;
    off += (bytes + 255) & ~(size_t)255;
    return p;
  };
  __bf16* Yb  = (__bf16*)alloc((size_t)N * HID * 2);  // gemm1 out; reused as G
  __bf16* Hb  = (__bf16*)alloc((size_t)N * HID * 2);  // relu(Â Y + b1)
  float* dinv = (float*)alloc((size_t)N * 4);
  int*   deg  = (int*)alloc((size_t)N * 4);
  int*   ptr  = (int*)alloc((size_t)(N + 1) * 4);
  int*   cur  = (int*)alloc((size_t)N * 4);
  int*   csrc = (int*)alloc((size_t)E * 4);
  float* cnrm = (float*)alloc((size_t)E * 4);
  __bf16* W1p = (__bf16*)alloc(32768 * 2);
  __bf16* Wcp = (__bf16*)alloc(16384 * 2);
  int*   bsum = (int*)alloc(256 * 4);
  (void)ws_size; (void)n_in; (void)out_size;

  hipMemsetAsync(deg, 0, (size_t)N * 4, stream);
  hipMemsetAsync(cur, 0, (size_t)N * 4, stream);

  int ge = (E + 255) / 256;
  int gn = (N + 255) / 256;
  int nb = (N + 256 * SITEMS - 1) / (256 * SITEMS);  // 49 blocks for N=100000
  count_deg_kernel<<<ge, 256, 0, stream>>>(ei, E, deg);
  dinv_kernel<<<gn, 256, 0, stream>>>(deg, dinv, N);
  scan_part_kernel<<<nb, 256, 0, stream>>>(deg, N, bsum);
  scan_bsum_kernel<<<1, 256, 0, stream>>>(bsum, nb);
  scan_final_kernel<<<nb, 256, 0, stream>>>(deg, N, bsum, ptr);
  fill_kernel<<<ge, 256, 0, stream>>>(ei, E, ptr, cur, dinv, csrc, cnrm);
  pack_w1_kernel<<<128, 256, 0, stream>>>(W1, W1p);
  pack_wc_kernel<<<64, 256, 0, stream>>>(Wmu, Wlv, Wcp);

  int gblk = (N + 127) / 128;
  gemm1_mfma<<<gblk, 256, 0, stream>>>(X, W1p, Yb, N);
  agg_kernel<<<N, 64, 0, stream>>>(Yb, ptr, csrc, cnrm, dinv, b1, Hb, 1);  // H = relu(ÂY+b1)
  agg_kernel<<<N, 64, 0, stream>>>(Hb, ptr, csrc, cnrm, dinv, b1, Yb, 0);  // G = ÂH
  gemm2_mfma<<<gblk, 256, 0, stream>>>(Yb, Wcp, bmu, blv, out, N);
}

// Round 4
// 481.280 us; speedup vs baseline: 2.3561x; 1.1373x over previous
//
#include <hip/hip_runtime.h>
#include <hip/hip_bf16.h>
#include <cstdint>

#define N_FEATS_IN 256
#define HID 128
#define OUTF 64
#define SITEMS 8  // elements per thread in hierarchical scan; 256*8=2048/block

typedef __bf16 bf16x8 __attribute__((ext_vector_type(8)));
typedef __bf16 bf16x2 __attribute__((ext_vector_type(2)));
typedef float f32x4 __attribute__((ext_vector_type(4)));

// ---- CSR build ----------------------------------------------------------
// count + rank in one pass: erank[e] = my slot within target bucket

__global__ __launch_bounds__(256) void count_deg_kernel(const int* __restrict__ ei, int E,
    int* __restrict__ deg, int* __restrict__ erank) {
  int e = blockIdx.x * 256 + threadIdx.x;
  if (e < E) erank[e] = atomicAdd(&deg[ei[E + e]], 1);  // col = target
}

__global__ __launch_bounds__(256) void dinv_kernel(const int* __restrict__ deg,
                                                   float* __restrict__ dinv, int n) {
  int i = blockIdx.x * 256 + threadIdx.x;
  if (i < n) dinv[i] = rsqrtf((float)(deg[i] + 1));  // +1 self-loop
}

// ---- hierarchical exclusive scan: ptr[0..n], ptr[n] = total -------------

__global__ __launch_bounds__(256) void scan_part_kernel(const int* __restrict__ cnt, int n,
                                                        int* __restrict__ bsum) {
  __shared__ int ts[256];
  const int t = threadIdx.x;
  int base = (blockIdx.x * 256 + t) * SITEMS;
  int s = 0;
#pragma unroll
  for (int i = 0; i < SITEMS; ++i) {
    int idx = base + i;
    if (idx < n) s += cnt[idx];
  }
  ts[t] = s;
  __syncthreads();
  for (int off = 128; off > 0; off >>= 1) {
    if (t < off) ts[t] += ts[t + off];
    __syncthreads();
  }
  if (t == 0) bsum[blockIdx.x] = ts[0];
}

__global__ __launch_bounds__(256) void scan_bsum_kernel(int* __restrict__ bsum, int nb) {
  __shared__ int ts[256];
  const int t = threadIdx.x;
  int v = (t < nb) ? bsum[t] : 0;
  ts[t] = v;
  __syncthreads();
  for (int off = 1; off < 256; off <<= 1) {
    int u = (t >= off) ? ts[t - off] : 0;
    __syncthreads();
    ts[t] += u;
    __syncthreads();
  }
  if (t < nb) bsum[t] = ts[t] - v;  // exclusive
}

__global__ __launch_bounds__(256) void scan_final_kernel(const int* __restrict__ cnt, int n,
    const int* __restrict__ bsum, int* __restrict__ ptr) {
  __shared__ int ts[256];
  const int t = threadIdx.x;
  int base = (blockIdx.x * 256 + t) * SITEMS;
  int loc[SITEMS];
  int s = 0;
#pragma unroll
  for (int i = 0; i < SITEMS; ++i) {
    int idx = base + i;
    loc[i] = (idx < n) ? cnt[idx] : 0;
    s += loc[i];
  }
  ts[t] = s;
  __syncthreads();
  for (int off = 1; off < 256; off <<= 1) {
    int u = (t >= off) ? ts[t - off] : 0;
    __syncthreads();
    ts[t] += u;
    __syncthreads();
  }
  int run = bsum[blockIdx.x] + ts[t] - s;  // exclusive prefix for this thread
#pragma unroll
  for (int i = 0; i < SITEMS; ++i) {
    int idx = base + i;
    if (idx < n) ptr[idx] = run;
    run += loc[i];
  }
  if (base < n && base + SITEMS >= n) ptr[n] = run;  // thread covering n-1
}

// no atomic: pos = ptr[c] + erank[e]; one 8B record store per edge

__global__ __launch_bounds__(256) void fill_kernel(const int* __restrict__ ei, int E,
    const int* __restrict__ ptr, const int* __restrict__ erank,
    const float* __restrict__ dinv, int2* __restrict__ erec) {
  int e = blockIdx.x * 256 + threadIdx.x;
  if (e < E) {
    int r = ei[e];       // source
    int c = ei[E + e];   // target
    int pos = ptr[c] + erank[e];
    int2 rec;
    rec.x = r;
    rec.y = __float_as_int(dinv[r] * dinv[c]);
    erec[pos] = rec;
  }
}

// ---- weight repack into MFMA B-fragment order ---------------------------
// B-frag for mfma_f32_16x16x32_bf16: lane l holds B[k = (l>>4)*8 + j][n = l&15]

__global__ __launch_bounds__(256) void pack_w1_kernel(const float* __restrict__ W,
                                                      __bf16* __restrict__ Wp) {
  int idx = blockIdx.x * 256 + threadIdx.x;  // 8s * 8t * 64l * 8j = 32768
  if (idx >= 32768) return;
  int j = idx & 7, l = (idx >> 3) & 63, t = (idx >> 9) & 7, s = idx >> 12;
  int k = s * 32 + (l >> 4) * 8 + j;
  int n = t * 16 + (l & 15);
  Wp[idx] = (__bf16)W[k * HID + n];
}

__global__ __launch_bounds__(256) void pack_wc_kernel(const float* __restrict__ Wmu,
    const float* __restrict__ Wlv, __bf16* __restrict__ Wp) {
  int idx = blockIdx.x * 256 + threadIdx.x;  // 4s * 8t * 64l * 8j = 16384
  if (idx >= 16384) return;
  int j = idx & 7, l = (idx >> 3) & 63, t = (idx >> 9) & 7, s = idx >> 12;
  int k = s * 32 + (l >> 4) * 8 + j;
  int g = t * 16 + (l & 15);
  float v = (g < OUTF) ? Wmu[k * OUTF + g] : Wlv[k * OUTF + (g - OUTF)];
  Wp[idx] = (__bf16)v;
}

// ---- GEMM1 (MFMA): Yb[N][128] = bf16( X[N][256] @ W1 ) ------------------

__global__ __launch_bounds__(256) void gemm1_mfma(const float* __restrict__ X,
    const __bf16* __restrict__ Wp, __bf16* __restrict__ Yb, int nrows) {
  const int lane = threadIdx.x & 63;
  const int wave = threadIdx.x >> 6;
  const int rb = blockIdx.x * 128 + wave * 32;
  const int lm = lane & 15;
  const int q = lane >> 4;

  f32x4 acc[2][8];
#pragma unroll
  for (int m = 0; m < 2; ++m)
#pragma unroll
    for (int t = 0; t < 8; ++t) acc[m][t] = (f32x4)0.f;

  int r0 = min(rb + lm, nrows - 1);
  int r1 = min(rb + 16 + lm, nrows - 1);
  const float* x0 = X + (size_t)r0 * N_FEATS_IN + q * 8;
  const float* x1 = X + (size_t)r1 * N_FEATS_IN + q * 8;
  const bf16x8* wp = (const bf16x8*)Wp;

#pragma unroll
  for (int s = 0; s < 8; ++s) {
    float4 u0 = ((const float4*)(x0 + s * 32))[0];
    float4 v0 = ((const float4*)(x0 + s * 32))[1];
    float4 u1 = ((const float4*)(x1 + s * 32))[0];
    float4 v1 = ((const float4*)(x1 + s * 32))[1];
    bf16x8 a0, a1;
    a0[0] = (__bf16)u0.x; a0[1] = (__bf16)u0.y; a0[2] = (__bf16)u0.z; a0[3] = (__bf16)u0.w;
    a0[4] = (__bf16)v0.x; a0[5] = (__bf16)v0.y; a0[6] = (__bf16)v0.z; a0[7] = (__bf16)v0.w;
    a1[0] = (__bf16)u1.x; a1[1] = (__bf16)u1.y; a1[2] = (__bf16)u1.z; a1[3] = (__bf16)u1.w;
    a1[4] = (__bf16)v1.x; a1[5] = (__bf16)v1.y; a1[6] = (__bf16)v1.z; a1[7] = (__bf16)v1.w;
#pragma unroll
    for (int t = 0; t < 8; ++t) {
      bf16x8 b = wp[(s * 8 + t) * 64 + lane];
      acc[0][t] = __builtin_amdgcn_mfma_f32_16x16x32_bf16(a0, b, acc[0][t], 0, 0, 0);
      acc[1][t] = __builtin_amdgcn_mfma_f32_16x16x32_bf16(a1, b, acc[1][t], 0, 0, 0);
    }
  }
  // D: col = lane&15, row = q*4 + reg
#pragma unroll
  for (int m = 0; m < 2; ++m) {
    int rowbase = rb + m * 16 + q * 4;
#pragma unroll
    for (int t = 0; t < 8; ++t) {
#pragma unroll
      for (int r = 0; r < 4; ++r) {
        int row = rowbase + r;
        if (row < nrows) Yb[(size_t)row * HID + t * 16 + lm] = (__bf16)acc[m][t][r];
      }
    }
  }
}

// ---- aggregation (bf16 in/out, f32 accumulate) --------------------------
// Fout[c] = dinv[c]^2*Fin[c] + sum_e norm[e]*Fin[src[e]]; 1 wave/node, 2 feats/lane

__global__ __launch_bounds__(64) void agg_kernel(const __bf16* __restrict__ Fin,
    const int* __restrict__ ptr, const int2* __restrict__ erec,
    const float* __restrict__ dinv, const float* __restrict__ bias,
    __bf16* __restrict__ Fout, int do_relu) {
  const int c = blockIdx.x;
  const int t = threadIdx.x;
  const float d = dinv[c];
  bf16x2 sv = ((const bf16x2*)(Fin + (size_t)c * HID))[t];
  float ax = d * d * (float)sv[0];
  float ay = d * d * (float)sv[1];
  const int beg = ptr[c], end = ptr[c + 1];
  int e = beg;
  for (; e + 4 <= end; e += 4) {
    int2 p0 = erec[e], p1 = erec[e + 1], p2 = erec[e + 2], p3 = erec[e + 3];
    float n0 = __int_as_float(p0.y), n1 = __int_as_float(p1.y);
    float n2 = __int_as_float(p2.y), n3 = __int_as_float(p3.y);
    bf16x2 v0 = ((const bf16x2*)(Fin + (size_t)p0.x * HID))[t];
    bf16x2 v1 = ((const bf16x2*)(Fin + (size_t)p1.x * HID))[t];
    bf16x2 v2 = ((const bf16x2*)(Fin + (size_t)p2.x * HID))[t];
    bf16x2 v3 = ((const bf16x2*)(Fin + (size_t)p3.x * HID))[t];
    ax = fmaf(n0, (float)v0[0], ax); ay = fmaf(n0, (float)v0[1], ay);
    ax = fmaf(n1, (float)v1[0], ax); ay = fmaf(n1, (float)v1[1], ay);
    ax = fmaf(n2, (float)v2[0], ax); ay = fmaf(n2, (float)v2[1], ay);
    ax = fmaf(n3, (float)v3[0], ax); ay = fmaf(n3, (float)v3[1], ay);
  }
  for (; e < end; ++e) {
    int2 p = erec[e];
    float nn = __int_as_float(p.y);
    bf16x2 v = ((const bf16x2*)(Fin + (size_t)p.x * HID))[t];
    ax = fmaf(nn, (float)v[0], ax);
    ay = fmaf(nn, (float)v[1], ay);
  }
  if (do_relu) {
    ax = fmaxf(ax + bias[2 * t], 0.f);
    ay = fmaxf(ay + bias[2 * t + 1], 0.f);
  }
  bf16x2 o;
  o[0] = (__bf16)ax;
  o[1] = (__bf16)ay;
  ((bf16x2*)(Fout + (size_t)c * HID))[t] = o;
}

// ---- GEMM2 (MFMA): [mu|lv] = Gb[N][128] @ Wc[128][128] + bias -----------

__global__ __launch_bounds__(256) void gemm2_mfma(const __bf16* __restrict__ Gb,
    const __bf16* __restrict__ Wp, const float* __restrict__ bmu,
    const float* __restrict__ blv, float* __restrict__ out, int nrows) {
  const int lane = threadIdx.x & 63;
  const int wave = threadIdx.x >> 6;
  const int rb = blockIdx.x * 128 + wave * 32;
  const int lm = lane & 15;
  const int q = lane >> 4;

  f32x4 acc[2][8];
#pragma unroll
  for (int m = 0; m < 2; ++m)
#pragma unroll
    for (int t = 0; t < 8; ++t) acc[m][t] = (f32x4)0.f;

  int r0 = min(rb + lm, nrows - 1);
  int r1 = min(rb + 16 + lm, nrows - 1);
  const __bf16* g0 = Gb + (size_t)r0 * HID + q * 8;
  const __bf16* g1 = Gb + (size_t)r1 * HID + q * 8;
  const bf16x8* wp = (const bf16x8*)Wp;

#pragma unroll
  for (int s = 0; s < 4; ++s) {
    bf16x8 a0 = *(const bf16x8*)(g0 + s * 32);
    bf16x8 a1 = *(const bf16x8*)(g1 + s * 32);
#pragma unroll
    for (int t = 0; t < 8; ++t) {
      bf16x8 b = wp[(s * 8 + t) * 64 + lane];
      acc[0][t] = __builtin_amdgcn_mfma_f32_16x16x32_bf16(a0, b, acc[0][t], 0, 0, 0);
      acc[1][t] = __builtin_amdgcn_mfma_f32_16x16x32_bf16(a1, b, acc[1][t], 0, 0, 0);
    }
  }
#pragma unroll
  for (int m = 0; m < 2; ++m) {
    int rowbase = rb + m * 16 + q * 4;
#pragma unroll
    for (int t = 0; t < 8; ++t) {
      int g = t * 16 + lm;
      float bv = (g < OUTF) ? bmu[g] : blv[g - OUTF];
      float* ob = (g < OUTF) ? (out + g) : (out + (size_t)nrows * OUTF + (g - OUTF));
#pragma unroll
      for (int r = 0; r < 4; ++r) {
        int row = rowbase + r;
        if (row < nrows) ob[(size_t)row * OUTF] = acc[m][t][r] + bv;
      }
    }
  }
}

// ---- launch -------------------------------------------------------------

extern "C" void kernel_launch(void* const* d_in, const int* in_sizes, int n_in,
                              void* d_out, int out_size, void* d_ws, size_t ws_size,
                              hipStream_t stream) {
  const float* X   = (const float*)d_in[0];
  const int*   ei  = (const int*)d_in[1];
  const float* W1  = (const float*)d_in[2];
  const float* b1  = (const float*)d_in[3];
  const float* Wmu = (const float*)d_in[4];
  const float* bmu = (const float*)d_in[5];
  const float* Wlv = (const float*)d_in[6];
  const float* blv = (const float*)d_in[7];
  float* out = (float*)d_out;

  const int N = in_sizes[0] / N_FEATS_IN;   // 100000
  const int E = in_sizes[1] / 2;            // 1600000

  char* ws = (char*)d_ws;
  size_t off = 0;
  auto alloc = [&](size_t bytes) -> void* {
    void* p = ws + off;
    off += (bytes + 255) & ~(size_t)255;
    return p;
  };
  __bf16* Yb  = (__bf16*)alloc((size_t)N * HID * 2);  // gemm1 out; reused as G
  __bf16* Hb  = (__bf16*)alloc((size_t)N * HID * 2);  // relu(Â Y + b1)
  float* dinv = (float*)alloc((size_t)N * 4);
  int*   deg  = (int*)alloc((size_t)N * 4);
  int*   ptr  = (int*)alloc((size_t)(N + 1) * 4);
  int*   erank = (int*)alloc((size_t)E * 4);
  int2*  erec = (int2*)alloc((size_t)E * 8);
  __bf16* W1p = (__bf16*)alloc(32768 * 2);
  __bf16* Wcp = (__bf16*)alloc(16384 * 2);
  int*   bsum = (int*)alloc(256 * 4);
  (void)ws_size; (void)n_in; (void)out_size;

  hipMemsetAsync(deg, 0, (size_t)N * 4, stream);

  int ge = (E + 255) / 256;
  int gn = (N + 255) / 256;
  int nb = (N + 256 * SITEMS - 1) / (256 * SITEMS);  // 49 blocks for N=100000
  count_deg_kernel<<<ge, 256, 0, stream>>>(ei, E, deg, erank);
  dinv_kernel<<<gn, 256, 0, stream>>>(deg, dinv, N);
  scan_part_kernel<<<nb, 256, 0, stream>>>(deg, N, bsum);
  scan_bsum_kernel<<<1, 256, 0, stream>>>(bsum, nb);
  scan_final_kernel<<<nb, 256, 0, stream>>>(deg, N, bsum, ptr);
  fill_kernel<<<ge, 256, 0, stream>>>(ei, E, ptr, erank, dinv, erec);
  pack_w1_kernel<<<128, 256, 0, stream>>>(W1, W1p);
  pack_wc_kernel<<<64, 256, 0, stream>>>(Wmu, Wlv, Wcp);

  int gblk = (N + 127) / 128;
  gemm1_mfma<<<gblk, 256, 0, stream>>>(X, W1p, Yb, N);
  agg_kernel<<<N, 64, 0, stream>>>(Yb, ptr, erec, dinv, b1, Hb, 1);  // H = relu(ÂY+b1)
  agg_kernel<<<N, 64, 0, stream>>>(Hb, ptr, erec, dinv, b1, Yb, 0);  // G = ÂH
  gemm2_mfma<<<gblk, 256, 0, stream>>>(Yb, Wcp, bmu, blv, out, N);
}